// Round 1
// baseline (9090.940 us; speedup 1.0000x reference)
//
#include <hip/hip_runtime.h>

#define F     4096
#define T     2048
#define NBLK  256
#define NTHR  1024
#define K     4      // ring slots; lockstep bounds skew so K>=2 is safe

// d_ws layout (NOTHING memset; harness re-poisons d_ws to 0xAA each launch):
//   [4096, 4096 + K*F*4) : ring[K][4096] u32 pairs {tag u16 << 16 | f16 bits}.
//   Poison 0xAAAAAAAA -> tag 0xAAAA = 43690, never equals a real tag (1..2049).
//   Data IS the flag: a pair is valid iff its tag matches.

typedef unsigned long long u64;
typedef unsigned int u32;
typedef unsigned short u16;

template <int CTRL>
__device__ __forceinline__ float dpp_add(float x) {
    int xi = __builtin_bit_cast(int, x);
    int yi = __builtin_amdgcn_update_dpp(0, xi, CTRL, 0xf, 0xf, false);
    return x + __builtin_bit_cast(float, yi);
}

// Full wave64 sum; total lands in lane 63. VALU-only.
__device__ __forceinline__ float wave_sum(float x) {
    x = dpp_add<0x111>(x); // row_shr:1
    x = dpp_add<0x112>(x); // row_shr:2
    x = dpp_add<0x114>(x); // row_shr:4
    x = dpp_add<0x118>(x); // row_shr:8
    x = dpp_add<0x142>(x); // row_bcast:15
    x = dpp_add<0x143>(x); // row_bcast:31
    return x;
}

#define PIN4(v) asm volatile("" : "+v"((v).x), "+v"((v).y), "+v"((v).z), "+v"((v).w))

__device__ __forceinline__ u64 cload_u64(const u64* p) {
    return __hip_atomic_load(p, __ATOMIC_RELAXED, __HIP_MEMORY_SCOPE_AGENT);
}
__device__ __forceinline__ void cstore_u32(u32* p, u32 v) {
    __hip_atomic_store(p, v, __ATOMIC_RELAXED, __HIP_MEMORY_SCOPE_AGENT);
}

__device__ __forceinline__ float half_to_f(u32 bits) {
    return (float)__builtin_bit_cast(_Float16, (u16)(bits & 0xffffu));
}

// Barrier-free cross-wave combine: partials are fixed-point quantized and
// packed {count at bit 32 | biased fixed in low 32}. One ds_add_rtn_u64 per
// contribution; the arriver whose returned count == N-1 owns the publish.
//   rows:   4 contribs, scale 2^24, bias 2^29 (|partial| <= ~13  < 32 hard)
//   readout:8 contribs, scale 2^22, bias 2^28 (|partial| <= ~46  < 64 hard)
// Biased values stay < 2^30 (2^29), so 4 (8) sums never carry into bit 32.
// Total bias = 2^31 in both cases -> un-bias is a single XOR 0x80000000.

__global__ __launch_bounds__(NTHR, 4) void rc_kernel(
    const float* __restrict__ x, const float* __restrict__ Wres,
    const float* __restrict__ wout, float* __restrict__ out,
    u32* __restrict__ ring)
{
    __shared__ __align__(16) float fl[2][F];  // staged feats, parity t&1 (32 KB)
    __shared__ u64 accf[2][16];               // row accumulators {cnt|fixed}
    __shared__ u64 acco[2][2];                // readout accumulators {cnt|fixed}

    const int tid  = threadIdx.x;
    const int b    = blockIdx.x;
    const int w    = tid >> 6;
    const int lane = tid & 63;
    const int wr   = w & 3;   // row-group (4 rows each)
    const int wk   = w >> 2;  // k-group (1024 k each)

    if (tid < 32) accf[tid >> 4][tid & 15] = 0ull;
    if (tid < 4)  acco[tid >> 1][tid & 1]  = 0ull;

    // ---- persistent W_res fragment: 4 rows x 16 k = 64 fp32 regs/lane ----
    const int row0 = b * 16 + wr * 4;
    const int kofs = wk * 1024 + lane * 4;
    float4 wreg[4][4];
#pragma unroll
    for (int j = 0; j < 4; ++j) {
        const float* wp = Wres + (size_t)(row0 + j) * F + kofs;
#pragma unroll
        for (int i = 0; i < 4; ++i)
            wreg[j][i] = *(const float4*)(wp + i * 256);
    }
#pragma unroll
    for (int j = 0; j < 4; ++j) {
        PIN4(wreg[j][0]); PIN4(wreg[j][1]); PIN4(wreg[j][2]); PIN4(wreg[j][3]);
    }

    // ---- persistent w_out fragment (fused readout): 8 fp32 regs/lane ----
    const int rrow = b * 2 + (wr & 1);
    const int i0   = (wr >> 1) * 2;
    const float* wop = wout + (size_t)rrow * F + kofs + i0 * 256;
    float4 wo0 = *(const float4*)(wop);
    float4 wo1 = *(const float4*)(wop + 256);
    PIN4(wo0); PIN4(wo1);

    // publish lanes: 15,31,47,63 own rows row0+g, g = lane>>4
    const int g    = lane >> 4;
    const bool pub = (lane & 15) == 15;

    // ---- x prefetch for step 0 (one value per publish lane) ----
    float xv = 0.f;
    if (pub) xv = x[(size_t)(row0 + g) * T + 0];

    __syncthreads();  // accf/acco init visible

    const int ep = w * 256 + lane * 4;  // this lane's staged chunk base

    for (int t = 0; t <= T; ++t) {
        const int par = t & 1;

        // ---- 1. poll feats_{t-1} pairs (data-as-flag) and stage to LDS ----
        if (t > 0) {
            const u32* rs = ring + (size_t)((t - 1) & (K - 1)) * F + ep;
            const u32 tag = (u32)t;
            u64 p01 = cload_u64((const u64*)rs);
            u64 p23 = cload_u64((const u64*)(rs + 2));
            bool ok = ((u32)(p01 & 0xffffffffu) >> 16 == tag)
                    & ((u32)(p01 >> 32) >> 16 == tag)
                    & ((u32)(p23 & 0xffffffffu) >> 16 == tag)
                    & ((u32)(p23 >> 32) >> 16 == tag);
            while (!__all(ok)) {
                __builtin_amdgcn_s_sleep(1);
                // unconditional dual reload: both IC loads in flight together
                p01 = cload_u64((const u64*)rs);
                p23 = cload_u64((const u64*)(rs + 2));
                ok = ((u32)(p01 & 0xffffffffu) >> 16 == tag)
                   & ((u32)(p01 >> 32) >> 16 == tag)
                   & ((u32)(p23 & 0xffffffffu) >> 16 == tag)
                   & ((u32)(p23 >> 32) >> 16 == tag);
            }
            float4 v;
            v.x = half_to_f((u32)(p01 & 0xffffffffu));
            v.y = half_to_f((u32)(p01 >> 32));
            v.z = half_to_f((u32)(p23 & 0xffffffffu));
            v.w = half_to_f((u32)(p23 >> 32));
            *(float4*)&fl[par][ep] = v;
        } else {
            *(float4*)&fl[par][ep] = make_float4(0.f, 0.f, 0.f, 0.f);
        }
        __syncthreads();  // (L) feats staged; only barrier in the loop

        // ---- 2. matvec from LDS + fused readout partial ----
        float4 f0 = *(const float4*)&fl[par][kofs + 0 * 256];
        float4 f1 = *(const float4*)&fl[par][kofs + 1 * 256];
        float4 f2 = *(const float4*)&fl[par][kofs + 2 * 256];
        float4 f3 = *(const float4*)&fl[par][kofs + 3 * 256];

        float acc0 = 0.f, acc1 = 0.f, acc2 = 0.f, acc3 = 0.f;
#define DOT_STEP(i, fv) \
        acc0 += wreg[0][i].x * fv.x + wreg[0][i].y * fv.y + wreg[0][i].z * fv.z + wreg[0][i].w * fv.w; \
        acc1 += wreg[1][i].x * fv.x + wreg[1][i].y * fv.y + wreg[1][i].z * fv.z + wreg[1][i].w * fv.w; \
        acc2 += wreg[2][i].x * fv.x + wreg[2][i].y * fv.y + wreg[2][i].z * fv.z + wreg[2][i].w * fv.w; \
        acc3 += wreg[3][i].x * fv.x + wreg[3][i].y * fv.y + wreg[3][i].z * fv.z + wreg[3][i].w * fv.w;
        DOT_STEP(0, f0)
        DOT_STEP(1, f1)
        DOT_STEP(2, f2)
        DOT_STEP(3, f3)
#undef DOT_STEP

        float4 ra, rb;
        if (i0 == 0) { ra = f0; rb = f1; } else { ra = f2; rb = f3; }
        float p = wo0.x * ra.x + wo0.y * ra.y + wo0.z * ra.z + wo0.w * ra.w
                + wo1.x * rb.x + wo1.y * rb.y + wo1.z * rb.z + wo1.w * rb.w;

        // ---- 3. wave reduce (lane63), scatter totals to publish lanes ----
        acc0 = wave_sum(acc0);
        acc1 = wave_sum(acc1);
        acc2 = wave_sum(acc2);
        acc3 = wave_sum(acc3);
        p    = wave_sum(p);

        float r0 = __shfl(acc0, 63), r1 = __shfl(acc1, 63),
              r2 = __shfl(acc2, 63), r3 = __shfl(acc3, 63);
        float myrow = (g == 0) ? r0 : (g == 1) ? r1 : (g == 2) ? r2 : r3;

        // ---- 4. barrier-free combine; last arriver publishes its row ----
        if (pub && t < T) {
            u32 biased = (u32)(__float2int_rn(myrow * 16777216.f) + 0x20000000);
            u64 c = (1ull << 32) | (u64)biased;
            u64 old = atomicAdd(&accf[par][wr * 4 + g], c);
            if ((u32)(old >> 32) == 3u) {  // I'm the 4th: total = old.lo + mine
                u32 tot = (u32)old + biased;
                int fx  = (int)(tot ^ 0x80000000u);   // remove 4*2^29 bias
                float s = (float)fx * (1.f / 16777216.f) + xv;
                s = fminf(1.f, fmaxf(-1.f, s));
                u32 hb = (u32)__builtin_bit_cast(u16, (_Float16)s);
                accf[par][wr * 4 + g] = 0ull;         // reset before publish
                cstore_u32(ring + (size_t)(t & (K - 1)) * F + b * 16 + wr * 4 + g,
                           ((u32)(t + 1) << 16) | hb);
            }
            // x prefetch for next step (off critical path)
            const int tn = (t + 1 < T) ? (t + 1) : (T - 1);
            xv = x[(size_t)(row0 + g) * T + tn];
        }

        // ---- 5. readout combine; last of 8 stores out[:, t-1] ----
        if (lane == 63 && t > 0) {
            u32 biased = (u32)(__float2int_rn(p * 4194304.f) + 0x10000000);
            u64 c = (1ull << 32) | (u64)biased;
            const int r = wr & 1;
            u64 old = atomicAdd(&acco[par][r], c);
            if ((u32)(old >> 32) == 7u) {  // I'm the 8th
                u32 tot = (u32)old + biased;
                int fx  = (int)(tot ^ 0x80000000u);   // remove 8*2^28 bias
                acco[par][r] = 0ull;
                out[(size_t)(b * 2 + r) * T + (t - 1)] = (float)fx * (1.f / 4194304.f);
            }
        }
        // Safety: fl parity-2 reuse (t vs t+2) and acc slot reuse are both
        // guarded by transitivity: any t+2 LDS op requires all blocks to have
        // consumed our t+1 publish, which requires every local wave to have
        // passed its t-tail (resets precede publishes in program order).
        // Ring slot reuse: lockstep over all blocks unchanged -> K=4 safe.
    }
}

extern "C" void kernel_launch(void* const* d_in, const int* in_sizes, int n_in,
                              void* d_out, int out_size, void* d_ws, size_t ws_size,
                              hipStream_t stream) {
    const float* x    = (const float*)d_in[0];
    const float* Wres = (const float*)d_in[1];
    const float* wout = (const float*)d_in[2];
    float* out        = (float*)d_out;
    u32* ring         = (u32*)((char*)d_ws + 4096);

    // no memset: ring tags are self-describing; 0xAA poison never matches.

    void* args[] = { (void*)&x, (void*)&Wres, (void*)&wout, (void*)&out,
                     (void*)&ring };
    (void)hipLaunchCooperativeKernel((const void*)rc_kernel, dim3(NBLK), dim3(NTHR),
                                     args, 0, stream);
}

// Round 2
// 8053.221 us; speedup vs baseline: 1.1289x; 1.1289x over previous
//
#include <hip/hip_runtime.h>

#define F     4096
#define T     2048
#define NBLK  256
#define NTHR  1024
#define K     4      // ring slots; lockstep bounds skew so K>=2 is safe

// d_ws layout (NOTHING memset; harness re-poisons d_ws to 0xAA each launch):
//   [4096, 4096 + K*F*4) : ring[K][4096] u32 pairs {tag u16 << 16 | f16 bits}.
//   Poison 0xAAAAAAAA -> tag 0xAAAA = 43690, never equals a real tag (1..2049).
//   Data IS the flag, end to end: ring pairs carry tags; the SAME raw pairs are
//   staged into LDS (no cvt), so LDS chunk validity is also per-pair tag==t.
//   Zero barriers in the main loop: fl / redp / redo are parity-double-buffered
//   tagged slots; reuse at t+2 is safe by transitivity through the all-to-all
//   (any t+2 write requires remote publishes at t+1, which require our publish
//   at t, which (wave0 program order) follows ALL our reads of parity-t slots).

typedef unsigned long long u64;
typedef unsigned int u32;
typedef unsigned short u16;

template <int CTRL>
__device__ __forceinline__ float dpp_add(float x) {
    int xi = __builtin_bit_cast(int, x);
    int yi = __builtin_amdgcn_update_dpp(0, xi, CTRL, 0xf, 0xf, false);
    return x + __builtin_bit_cast(float, yi);
}

// Full wave64 sum; total lands in lane 63. VALU-only.
__device__ __forceinline__ float wave_sum(float x) {
    x = dpp_add<0x111>(x); // row_shr:1
    x = dpp_add<0x112>(x); // row_shr:2
    x = dpp_add<0x114>(x); // row_shr:4
    x = dpp_add<0x118>(x); // row_shr:8
    x = dpp_add<0x142>(x); // row_bcast:15
    x = dpp_add<0x143>(x); // row_bcast:31
    return x;
}

#define PIN4(v) asm volatile("" : "+v"((v).x), "+v"((v).y), "+v"((v).z), "+v"((v).w))

__device__ __forceinline__ u64 cload_u64(const u64* p) {
    return __hip_atomic_load(p, __ATOMIC_RELAXED, __HIP_MEMORY_SCOPE_AGENT);
}
__device__ __forceinline__ void cstore_u32(u32* p, u32 v) {
    __hip_atomic_store(p, v, __ATOMIC_RELAXED, __HIP_MEMORY_SCOPE_AGENT);
}
__device__ __forceinline__ u64 lds_load64(const u64* p) {
    return __hip_atomic_load(p, __ATOMIC_RELAXED, __HIP_MEMORY_SCOPE_WORKGROUP);
}
__device__ __forceinline__ void lds_store64(u64* p, u64 v) {
    __hip_atomic_store(p, v, __ATOMIC_RELAXED, __HIP_MEMORY_SCOPE_WORKGROUP);
}

__device__ __forceinline__ float half_to_f(u32 bits) {
    return (float)__builtin_bit_cast(_Float16, (u16)(bits & 0xffffu));
}

__global__ __launch_bounds__(NTHR, 4) void rc_kernel(
    const float* __restrict__ x, const float* __restrict__ Wres,
    const float* __restrict__ wout, float* __restrict__ out,
    u32* __restrict__ ring)
{
    __shared__ __align__(16) u32 fl[2][F];   // staged RAW pairs, parity t&1 (32 KB)
    __shared__ u64 redp[2][64];              // row partials {tag32|f32}, slot=row*4+kg
    __shared__ u64 redo[2][16];              // readout partials {tag32|f32}

    const int tid  = threadIdx.x;
    const int b    = blockIdx.x;
    const int w    = tid >> 6;
    const int lane = tid & 63;
    const int wr   = w & 3;   // row-group (4 rows each)
    const int wk   = w >> 2;  // k-group (1024 k each)
    const int g    = lane >> 4;

    // ---- prologue LDS init: tags that never match (t in [0,2048]) ----
#pragma unroll
    for (int i = 0; i < 8; ++i) ((u32*)fl)[tid + i * NTHR] = 0xFFFF0000u;
    if (tid < 128) ((u64*)redp)[tid] = 0ull;
    if (tid < 32)  ((u64*)redo)[tid] = 0ull;

    // ---- persistent W_res fragment: 4 rows x 16 k = 64 fp32 regs/lane ----
    const int row0 = b * 16 + wr * 4;
    const int kofs = wk * 1024 + lane * 4;
    float4 wreg[4][4];
#pragma unroll
    for (int j = 0; j < 4; ++j) {
        const float* wp = Wres + (size_t)(row0 + j) * F + kofs;
#pragma unroll
        for (int i = 0; i < 4; ++i)
            wreg[j][i] = *(const float4*)(wp + i * 256);
    }
#pragma unroll
    for (int j = 0; j < 4; ++j) {
        PIN4(wreg[j][0]); PIN4(wreg[j][1]); PIN4(wreg[j][2]); PIN4(wreg[j][3]);
    }

    // ---- persistent w_out fragment (fused readout): 8 fp32 regs/lane ----
    const int rrow = b * 2 + (wr & 1);
    const int i0   = (wr >> 1) * 2;
    const float* wop = wout + (size_t)rrow * F + kofs + i0 * 256;
    float4 wo0 = *(const float4*)(wop);
    float4 wo1 = *(const float4*)(wop + 256);
    PIN4(wo0); PIN4(wo1);

    __syncthreads();  // prologue only: LDS tag init visible

    // ---- x prefetch for step 0: wave0 publish lanes (lane&3)==0 own row lane>>2
    float xv = 0.f;
    if (w == 0 && (lane & 3) == 0) xv = x[(size_t)(b * 16 + (lane >> 2)) * T + 0];

    const int ep = w * 256 + lane * 4;  // staged chunk slice base (u32 units)

    for (int t = 0; t <= T; ++t) {
        const int par = t & 1;
        const u32 ctag = (u32)t;

        // ---- 1. stage my 4 raw pairs (fire per-lane as soon as valid) ----
        if (t > 0) {
            const u32* rs = ring + (size_t)((t - 1) & (K - 1)) * F + ep;
            bool done = false;
            for (;;) {
                if (!done) {
                    u64 p01 = cload_u64((const u64*)rs);
                    u64 p23 = cload_u64((const u64*)(rs + 2));
                    bool ok = ((u32)p01 >> 16 == ctag) & ((u32)(p01 >> 32) >> 16 == ctag)
                            & ((u32)p23 >> 16 == ctag) & ((u32)(p23 >> 32) >> 16 == ctag);
                    if (ok) {
                        lds_store64((u64*)&fl[par][ep], p01);
                        lds_store64((u64*)&fl[par][ep + 2], p23);
                        done = true;
                    }
                }
                if (__all(done)) break;
                __builtin_amdgcn_s_sleep(1);
            }
        } else {
            // t==0: feats_{-1}=0, tag 0 (prologue init 0xFFFF never false-matches)
            lds_store64((u64*)&fl[0][ep], 0ull);
            lds_store64((u64*)&fl[0][ep + 2], 0ull);
        }

        // ---- 2. incremental consume: FMA each chunk as it lands in LDS ----
        float acc0 = 0.f, acc1 = 0.f, acc2 = 0.f, acc3 = 0.f, p = 0.f;
        u32 pend = 0xFu;
        while (pend) {
#pragma unroll
            for (int i = 0; i < 4; ++i) {
                if (pend & (1u << i)) {
                    const u64* ap = (const u64*)&fl[par][kofs + i * 256];
                    u64 a  = lds_load64(ap);
                    u64 c2 = lds_load64(ap + 1);
                    bool ok = ((u32)a  >> 16 == ctag) & ((u32)(a  >> 32) >> 16 == ctag)
                            & ((u32)c2 >> 16 == ctag) & ((u32)(c2 >> 32) >> 16 == ctag);
                    if (__all(ok)) {
                        float4 f;
                        f.x = half_to_f((u32)a);  f.y = half_to_f((u32)(a  >> 32));
                        f.z = half_to_f((u32)c2); f.w = half_to_f((u32)(c2 >> 32));
                        acc0 += wreg[0][i].x * f.x + wreg[0][i].y * f.y + wreg[0][i].z * f.z + wreg[0][i].w * f.w;
                        acc1 += wreg[1][i].x * f.x + wreg[1][i].y * f.y + wreg[1][i].z * f.z + wreg[1][i].w * f.w;
                        acc2 += wreg[2][i].x * f.x + wreg[2][i].y * f.y + wreg[2][i].z * f.z + wreg[2][i].w * f.w;
                        acc3 += wreg[3][i].x * f.x + wreg[3][i].y * f.y + wreg[3][i].z * f.z + wreg[3][i].w * f.w;
                        if (i == i0)
                            p += wo0.x * f.x + wo0.y * f.y + wo0.z * f.z + wo0.w * f.w;
                        else if (i == i0 + 1)
                            p += wo1.x * f.x + wo1.y * f.y + wo1.z * f.z + wo1.w * f.w;
                        pend &= ~(1u << i);
                    }
                }
            }
        }

        // ---- 3. wave reduce; tagged partials to LDS (no barrier) ----
        acc0 = wave_sum(acc0);
        acc1 = wave_sum(acc1);
        acc2 = wave_sum(acc2);
        acc3 = wave_sum(acc3);
        p    = wave_sum(p);

        float r0 = __shfl(acc0, 63), r1 = __shfl(acc1, 63),
              r2 = __shfl(acc2, 63), r3 = __shfl(acc3, 63);
        const u32 rt = (u32)(t + 1);
        if ((lane & 15) == 15) {  // lanes 15/31/47/63 carry rows g=0..3
            float myrow = (g == 0) ? r0 : (g == 1) ? r1 : (g == 2) ? r2 : r3;
            lds_store64(&redp[par][(wr * 4 + g) * 4 + wk],
                        ((u64)rt << 32) | (u64)__builtin_bit_cast(u32, myrow));
        }
        if (lane == 63) {
            lds_store64(&redo[par][(wr & 1) * 8 + wk * 2 + (wr >> 1)],
                        ((u64)rt << 32) | (u64)__builtin_bit_cast(u32, p));
        }

        // ---- 4. wave0: poll partials, combine, SINGLE coalesced publish ----
        if (w == 0) {
            if (t < T) {
                u64 q, q2 = 0;
                for (;;) {  // lane L: redp slot L (row L>>2, kg L&3); lanes<16 also redo
                    q = lds_load64(&redp[par][lane]);
                    bool ok = ((u32)(q >> 32) == rt);
                    if (lane < 16) {
                        q2 = lds_load64(&redo[par][lane]);
                        ok &= ((u32)(q2 >> 32) == rt);
                    }
                    if (__all(ok)) break;
                }
                float v = __builtin_bit_cast(float, (u32)q);
                v += __shfl_xor(v, 1);  // quad sum: 4 k-group partials of row lane>>2
                v += __shfl_xor(v, 2);
                if ((lane & 3) == 0) {
                    float s = v + xv;
                    s = fminf(1.f, fmaxf(-1.f, s));
                    u32 hb = (u32)__builtin_bit_cast(u16, (_Float16)s);
                    // 16 active lanes, contiguous addresses -> one 64B transaction
                    cstore_u32(ring + (size_t)(t & (K - 1)) * F + b * 16 + (lane >> 2),
                               (rt << 16) | hb);
                    const int tn = (t + 1 < T) ? (t + 1) : (T - 1);
                    xv = x[(size_t)(b * 16 + (lane >> 2)) * T + tn];  // off crit path
                }
                if (t > 0 && lane < 16) {
                    float rv = __builtin_bit_cast(float, (u32)q2);
                    rv += __shfl_xor(rv, 1);
                    rv += __shfl_xor(rv, 2);
                    rv += __shfl_xor(rv, 4);
                    if ((lane & 7) == 0)
                        out[(size_t)(b * 2 + (lane >> 3)) * T + (t - 1)] = rv;
                }
            } else {
                // t==T: no publish; only drain the last readout column
                if (lane < 16) {
                    u64 q2;
                    for (;;) {
                        q2 = lds_load64(&redo[par][lane]);
                        if (__all((u32)(q2 >> 32) == rt)) break;
                    }
                    float rv = __builtin_bit_cast(float, (u32)q2);
                    rv += __shfl_xor(rv, 1);
                    rv += __shfl_xor(rv, 2);
                    rv += __shfl_xor(rv, 4);
                    if ((lane & 7) == 0)
                        out[(size_t)(b * 2 + (lane >> 3)) * T + (T - 1)] = rv;
                }
            }
        }
        // Hazard audit (t vs t+2 parity reuse, no barriers):
        //  fl:   stager at t+2 <- ring(t+1) <- remote publish t+1 <- remote
        //        consumed feats_t <- our publish t <- wave0 saw ALL redp tags t+1
        //        <- every consumer wave finished its fl[par] reads at t.
        //  redp: writer at t+2 <- (same chain) <- wave0's redp reads at t done
        //        (poll reads precede publish in wave0 program order).
        //  redo: polled in the SAME pre-publish loop as redp -> same chain.
        //  ring: K=4, lockstep all-to-all ordering unchanged.
    }
}

extern "C" void kernel_launch(void* const* d_in, const int* in_sizes, int n_in,
                              void* d_out, int out_size, void* d_ws, size_t ws_size,
                              hipStream_t stream) {
    const float* x    = (const float*)d_in[0];
    const float* Wres = (const float*)d_in[1];
    const float* wout = (const float*)d_in[2];
    float* out        = (float*)d_out;
    u32* ring         = (u32*)((char*)d_ws + 4096);

    // no memset: ring tags are self-describing; 0xAA poison never matches.

    void* args[] = { (void*)&x, (void*)&Wres, (void*)&wout, (void*)&out,
                     (void*)&ring };
    (void)hipLaunchCooperativeKernel((const void*)rc_kernel, dim3(NBLK), dim3(NTHR),
                                     args, 0, stream);
}

// Round 3
// 7898.563 us; speedup vs baseline: 1.1510x; 1.0196x over previous
//
#include <hip/hip_runtime.h>

#define F     4096
#define T     2048
#define NBLK  256
#define NTHR  1024
#define K     4      // ring slots; lockstep bounds skew so K>=2 is safe

// d_ws layout (NOTHING memset; harness re-poisons d_ws to 0xAA each launch):
//   [4096, 4096 + K*F*4) : ring[K][4096] u32 pairs {tag u16 << 16 | f16 bits}.
//   Poison 0xAAAAAAAA -> tag 0xAAAA = 43690, never equals a real tag (1..2049).
//   Data IS the flag: a pair is valid iff its tag matches; producer stores are
//   fire-and-forget; consumers accept fresh chunks immediately.
//
// vs the 6958us baseline: sync(A) + red/redo arrays are replaced by tagged LDS
// partial slots (redq/redqo, {tag32|f32} per u64). ONLY wave0 spins on redq
// (combine+publish) and ONLY wave1 spins on redqo (out store); waves 2..15 go
// straight to the next ring poll. R2 showed 16 spinning waves on LDS tags is a
// loss; 1-2 spinning waves on conflict-free padded slots is the cheap version.

typedef unsigned long long u64;
typedef unsigned int u32;
typedef unsigned short u16;

template <int CTRL>
__device__ __forceinline__ float dpp_add(float x) {
    int xi = __builtin_bit_cast(int, x);
    int yi = __builtin_amdgcn_update_dpp(0, xi, CTRL, 0xf, 0xf, false);
    return x + __builtin_bit_cast(float, yi);
}

// Full wave64 sum; total lands in lane 63. VALU-only.
__device__ __forceinline__ float wave_sum(float x) {
    x = dpp_add<0x111>(x); // row_shr:1
    x = dpp_add<0x112>(x); // row_shr:2
    x = dpp_add<0x114>(x); // row_shr:4
    x = dpp_add<0x118>(x); // row_shr:8
    x = dpp_add<0x142>(x); // row_bcast:15
    x = dpp_add<0x143>(x); // row_bcast:31
    return x;
}

#define PIN4(v) asm volatile("" : "+v"((v).x), "+v"((v).y), "+v"((v).z), "+v"((v).w))

__device__ __forceinline__ u64 cload_u64(const u64* p) {
    return __hip_atomic_load(p, __ATOMIC_RELAXED, __HIP_MEMORY_SCOPE_AGENT);
}
__device__ __forceinline__ void cstore_u32(u32* p, u32 v) {
    __hip_atomic_store(p, v, __ATOMIC_RELAXED, __HIP_MEMORY_SCOPE_AGENT);
}

__device__ __forceinline__ float half_to_f(u32 bits) {
    return (float)__builtin_bit_cast(_Float16, (u16)(bits & 0xffffu));
}

__device__ __forceinline__ u64 pack_tf(u32 tag, float v) {
    return ((u64)tag << 32) | (u64)__builtin_bit_cast(u32, v);
}

__global__ __launch_bounds__(NTHR, 4) void rc_kernel(
    const float* __restrict__ x, const float* __restrict__ Wres,
    const float* __restrict__ wout, float* __restrict__ out,
    u32* __restrict__ ring)
{
    __shared__ __align__(16) float fl[F];       // staged feats vector (16 KB)
    __shared__ volatile u64 redq[2][16][5];     // {tag32|f32} [par][row][kg], +pad
    __shared__ volatile u64 redqo[2][16];       // {tag32|f32} [par][wave]

    const int tid  = threadIdx.x;
    const int b    = blockIdx.x;
    const int w    = tid >> 6;
    const int lane = tid & 63;
    const int wr   = w & 3;   // row-group (4 rows each)
    const int wk   = w >> 2;  // k-group (1024 k each)

    // prologue: tags 0 never match rt in [1,2049]
    if (tid < 160) ((u64*)redq)[tid]  = 0ull;
    if (tid < 32)  ((u64*)redqo)[tid] = 0ull;

    // ---- persistent W_res fragment: 4 rows x 16 k = 64 fp32 regs/lane ----
    const int row0 = b * 16 + wr * 4;
    const int kofs = wk * 1024 + lane * 4;
    float4 wreg[4][4];
#pragma unroll
    for (int j = 0; j < 4; ++j) {
        const float* wp = Wres + (size_t)(row0 + j) * F + kofs;
#pragma unroll
        for (int i = 0; i < 4; ++i)
            wreg[j][i] = *(const float4*)(wp + i * 256);
    }
#pragma unroll
    for (int j = 0; j < 4; ++j) {
        PIN4(wreg[j][0]); PIN4(wreg[j][1]); PIN4(wreg[j][2]); PIN4(wreg[j][3]);
    }

    // ---- persistent w_out fragment (fused readout): 8 fp32 regs/lane ----
    const int rrow = b * 2 + (wr & 1);
    const int i0   = (wr >> 1) * 2;
    const float* wop = wout + (size_t)rrow * F + kofs + i0 * 256;
    float4 wo0 = *(const float4*)(wop);
    float4 wo1 = *(const float4*)(wop + 256);
    PIN4(wo0); PIN4(wo1);

    // ---- x prefetch for step 0 ----
    float xval = 0.f;
    if (tid < 16) xval = x[(size_t)(b * 16 + tid) * T + 0];

    __syncthreads();  // prologue only: redq/redqo init visible

    const int ep = w * 256 + lane * 4;  // this lane's chunk base (elements)

    for (int t = 0; t <= T; ++t) {
        const int pb  = t & 1;
        const u32 rt  = (u32)(t + 1);

        // ---- 1. poll feats_{t-1} pairs (data-as-flag) and stage to LDS ----
        if (t > 0) {
            const u32* rs = ring + (size_t)((t - 1) & (K - 1)) * F + ep;
            const u32 tag = (u32)t;
            u64 p01 = cload_u64((const u64*)rs);
            u64 p23 = cload_u64((const u64*)(rs + 2));
            bool okA = ((u32)(p01 & 0xffffffffu) >> 16 == tag)
                     & ((u32)(p01 >> 32) >> 16 == tag);
            bool okB = ((u32)(p23 & 0xffffffffu) >> 16 == tag)
                     & ((u32)(p23 >> 32) >> 16 == tag);
            while (!__all(okA & okB)) {
                __builtin_amdgcn_s_sleep(1);
                if (!okA) {
                    p01 = cload_u64((const u64*)rs);
                    okA = ((u32)(p01 & 0xffffffffu) >> 16 == tag)
                        & ((u32)(p01 >> 32) >> 16 == tag);
                }
                if (!okB) {
                    p23 = cload_u64((const u64*)(rs + 2));
                    okB = ((u32)(p23 & 0xffffffffu) >> 16 == tag)
                        & ((u32)(p23 >> 32) >> 16 == tag);
                }
            }
            float4 v;
            v.x = half_to_f((u32)(p01 & 0xffffffffu));
            v.y = half_to_f((u32)(p01 >> 32));
            v.z = half_to_f((u32)(p23 & 0xffffffffu));
            v.w = half_to_f((u32)(p23 >> 32));
            *(float4*)&fl[ep] = v;
        } else {
            *(float4*)&fl[ep] = make_float4(0.f, 0.f, 0.f, 0.f);  // feats_{-1}=0
        }
        __syncthreads();  // (L) feats staged; the only per-step barrier

        // ---- 2. matvec from LDS + fused readout partial ----
        float4 f0 = *(const float4*)&fl[kofs + 0 * 256];
        float4 f1 = *(const float4*)&fl[kofs + 1 * 256];
        float4 f2 = *(const float4*)&fl[kofs + 2 * 256];
        float4 f3 = *(const float4*)&fl[kofs + 3 * 256];

        float acc0 = 0.f, acc1 = 0.f, acc2 = 0.f, acc3 = 0.f;
#define DOT_STEP(i, fv) \
        acc0 += wreg[0][i].x * fv.x + wreg[0][i].y * fv.y + wreg[0][i].z * fv.z + wreg[0][i].w * fv.w; \
        acc1 += wreg[1][i].x * fv.x + wreg[1][i].y * fv.y + wreg[1][i].z * fv.z + wreg[1][i].w * fv.w; \
        acc2 += wreg[2][i].x * fv.x + wreg[2][i].y * fv.y + wreg[2][i].z * fv.z + wreg[2][i].w * fv.w; \
        acc3 += wreg[3][i].x * fv.x + wreg[3][i].y * fv.y + wreg[3][i].z * fv.z + wreg[3][i].w * fv.w;
        DOT_STEP(0, f0)
        DOT_STEP(1, f1)
        DOT_STEP(2, f2)
        DOT_STEP(3, f3)
#undef DOT_STEP

        float4 ra, rb;
        if (i0 == 0) { ra = f0; rb = f1; } else { ra = f2; rb = f3; }
        float p = wo0.x * ra.x + wo0.y * ra.y + wo0.z * ra.z + wo0.w * ra.w
                + wo1.x * rb.x + wo1.y * rb.y + wo1.z * rb.z + wo1.w * rb.w;

        // ---- 3. wave reduce; tagged partials to LDS (NO barrier) ----
        acc0 = wave_sum(acc0);
        acc1 = wave_sum(acc1);
        acc2 = wave_sum(acc2);
        acc3 = wave_sum(acc3);
        p    = wave_sum(p);
        if (lane == 63) {
            redq[pb][wr * 4 + 0][wk] = pack_tf(rt, acc0);
            redq[pb][wr * 4 + 1][wk] = pack_tf(rt, acc1);
            redq[pb][wr * 4 + 2][wk] = pack_tf(rt, acc2);
            redq[pb][wr * 4 + 3][wk] = pack_tf(rt, acc3);
            redqo[pb][w] = pack_tf(rt, p);
        }

        // ---- 4. wave0: spin on row partial tags, combine, coalesced publish --
        if (w == 0 && t < T) {
            __builtin_amdgcn_s_setprio(1);
            const int rr = lane & 15;         // lanes 16+ replicate -> broadcast
            u64 q0, q1, q2, q3; bool ok;
            do {
                q0 = redq[pb][rr][0]; q1 = redq[pb][rr][1];
                q2 = redq[pb][rr][2]; q3 = redq[pb][rr][3];
                ok = ((u32)(q0 >> 32) == rt) & ((u32)(q1 >> 32) == rt)
                   & ((u32)(q2 >> 32) == rt) & ((u32)(q3 >> 32) == rt);
            } while (!__all(ok));
            float s = (__builtin_bit_cast(float, (u32)q0) + __builtin_bit_cast(float, (u32)q1))
                    + (__builtin_bit_cast(float, (u32)q2) + __builtin_bit_cast(float, (u32)q3))
                    + xval;
            s = fminf(1.f, fmaxf(-1.f, s));
            u32 hb = (u32)__builtin_bit_cast(u16, (_Float16)s);
            if (lane < 16) {
                // 16 lanes, contiguous addresses -> one 64B transaction
                cstore_u32(ring + (size_t)(t & (K - 1)) * F + b * 16 + lane,
                           (rt << 16) | hb);
            }
            __builtin_amdgcn_s_setprio(0);
            if (lane < 16) {
                const int tn = (t + 1 < T) ? (t + 1) : (T - 1);
                xval = x[(size_t)(b * 16 + lane) * T + tn];  // off critical path
            }
        }

        // ---- 5. wave1: spin on readout tags, store out[:, t-1] ----
        if (w == 1 && t > 0) {
            const int rr = lane & 15;
            u64 q; bool ok;
            do {
                q = redqo[pb][rr];
                ok = ((u32)(q >> 32) == rt);
            } while (!__all(ok));
            float v = __builtin_bit_cast(float, (u32)q);
            v += __shfl_xor(v, 2);   // fold waves, keeping bit0 (row parity)
            v += __shfl_xor(v, 4);
            v += __shfl_xor(v, 8);
            if (lane < 2)
                out[(size_t)(b * 2 + lane) * T + (t - 1)] = v;
        }

        // Hazard audit (no sync(A)):
        //  fl (single-buffered): stager at t+1 <- ring(t) <- our publish t <-
        //    wave0 saw redq tags t+1... from EVERY wave; a wave's redq write is
        //    data-dependent on its fl reads -> all fl reads of step t complete
        //    before any t+1 staging write. sync(L) covers stage(t)->read(t).
        //  redq/redqo parity-2 reuse (t vs t+2): writer at t+2 <- sync(L,t+2)
        //    <- ring(t+1) <- our publish(t+1) <- wave0/wave1 finished their
        //    parity-p reads at t (program order before publish t, t+1).
        //  ring: K=4, lockstep all-to-all ordering unchanged; skew <= 1 step.
    }
}

extern "C" void kernel_launch(void* const* d_in, const int* in_sizes, int n_in,
                              void* d_out, int out_size, void* d_ws, size_t ws_size,
                              hipStream_t stream) {
    const float* x    = (const float*)d_in[0];
    const float* Wres = (const float*)d_in[1];
    const float* wout = (const float*)d_in[2];
    float* out        = (float*)d_out;
    u32* ring         = (u32*)((char*)d_ws + 4096);

    // no memset: ring tags are self-describing; 0xAA poison never matches.

    void* args[] = { (void*)&x, (void*)&Wres, (void*)&wout, (void*)&out,
                     (void*)&ring };
    (void)hipLaunchCooperativeKernel((const void*)rc_kernel, dim3(NBLK), dim3(NTHR),
                                     args, 0, stream);
}

// Round 4
// 7709.889 us; speedup vs baseline: 1.1791x; 1.0245x over previous
//
#include <hip/hip_runtime.h>

#define F     4096
#define T     2048
#define NBLK  256
#define NTHR  1024
#define K     4      // ring slots; lockstep bounds skew so K>=2 is safe

// d_ws layout (NOTHING memset; harness re-poisons d_ws to 0xAA each launch):
//   [4096, 4096 + K*F*4) : ring[K][4096] u32 pairs {tag u16 << 16 | f16 bits}.
//   Poison 0xAAAAAAAA -> tag 0xAAAA = 43690, never equals a real tag (1..2049).
//   Data IS the flag: a pair is valid iff its tag matches; producer stores are
//   fire-and-forget; consumers accept fresh chunks immediately (overlapped).
//
// R1-R3 lesson: every spin-replacement of a barrier regressed (+13..30%) --
// sleeping at s_barrier is free, spinning steals issue slots + fabric BW.
// R4 = R0 baseline schedule exactly, with the post-barrier publish tail
// shortened: lane-parallel combine (coalesced LDS read + 2 shfl_xor instead
// of 4 scattered reads + serial adds), xor-mask tag checks in the poll loop,
// and a setprio window around wave0's combine+publish.

typedef unsigned long long u64;
typedef unsigned int u32;
typedef unsigned short u16;

template <int CTRL>
__device__ __forceinline__ float dpp_add(float x) {
    int xi = __builtin_bit_cast(int, x);
    int yi = __builtin_amdgcn_update_dpp(0, xi, CTRL, 0xf, 0xf, false);
    return x + __builtin_bit_cast(float, yi);
}

// Full wave64 sum; total lands in lane 63. VALU-only.
__device__ __forceinline__ float wave_sum(float x) {
    x = dpp_add<0x111>(x); // row_shr:1
    x = dpp_add<0x112>(x); // row_shr:2
    x = dpp_add<0x114>(x); // row_shr:4
    x = dpp_add<0x118>(x); // row_shr:8
    x = dpp_add<0x142>(x); // row_bcast:15
    x = dpp_add<0x143>(x); // row_bcast:31
    return x;
}

#define PIN4(v) asm volatile("" : "+v"((v).x), "+v"((v).y), "+v"((v).z), "+v"((v).w))

__device__ __forceinline__ u64 cload_u64(const u64* p) {
    return __hip_atomic_load(p, __ATOMIC_RELAXED, __HIP_MEMORY_SCOPE_AGENT);
}
__device__ __forceinline__ void cstore_u32(u32* p, u32 v) {
    __hip_atomic_store(p, v, __ATOMIC_RELAXED, __HIP_MEMORY_SCOPE_AGENT);
}

__device__ __forceinline__ float half_to_f(u32 bits) {
    return (float)__builtin_bit_cast(_Float16, (u16)(bits & 0xffffu));
}

__global__ __launch_bounds__(NTHR, 4) void rc_kernel(
    const float* __restrict__ x, const float* __restrict__ Wres,
    const float* __restrict__ wout, float* __restrict__ out,
    u32* __restrict__ ring)
{
    __shared__ __align__(16) float fl[F];     // staged feats vector (16 KB)
    __shared__ __align__(16) float red[2][16][4];  // matvec partials [par][wave][row]
    __shared__ float redo[2][16];             // readout partials [par][wave]

    const int tid  = threadIdx.x;
    const int b    = blockIdx.x;
    const int w    = tid >> 6;
    const int lane = tid & 63;
    const int wr   = w & 3;   // row-group (4 rows each)
    const int wk   = w >> 2;  // k-group (1024 k each)

    // ---- persistent W_res fragment: 4 rows x 16 k = 64 fp32 regs/lane ----
    const int row0 = b * 16 + wr * 4;
    const int kofs = wk * 1024 + lane * 4;
    float4 wreg[4][4];
#pragma unroll
    for (int j = 0; j < 4; ++j) {
        const float* wp = Wres + (size_t)(row0 + j) * F + kofs;
#pragma unroll
        for (int i = 0; i < 4; ++i)
            wreg[j][i] = *(const float4*)(wp + i * 256);
    }
#pragma unroll
    for (int j = 0; j < 4; ++j) {
        PIN4(wreg[j][0]); PIN4(wreg[j][1]); PIN4(wreg[j][2]); PIN4(wreg[j][3]);
    }

    // ---- persistent w_out fragment (fused readout): 8 fp32 regs/lane ----
    const int rrow = b * 2 + (wr & 1);
    const int i0   = (wr >> 1) * 2;
    const float* wop = wout + (size_t)rrow * F + kofs + i0 * 256;
    float4 wo0 = *(const float4*)(wop);
    float4 wo1 = *(const float4*)(wop + 256);
    PIN4(wo0); PIN4(wo1);

    // ---- x prefetch for step 0 ----
    float xval = 0.f;
    if (tid < 16) xval = x[(size_t)(b * 16 + tid) * T + 0];

    const int ep = w * 256 + lane * 4;  // this lane's chunk base (elements)

    for (int t = 0; t <= T; ++t) {
        // ---- 1. poll feats_{t-1} pairs (data-as-flag) and stage to LDS ----
        if (t > 0) {
            const u32* rs = ring + (size_t)((t - 1) & (K - 1)) * F + ep;
            const u32 tag = (u32)t;
            // replicated-tag masks: one xor/and/cmp validates both pairs of a u64
            const u64 etag = ((u64)tag << 48) | ((u64)tag << 16);
            const u64 emsk = 0xffff0000ffff0000ull;
            u64 p01 = cload_u64((const u64*)rs);
            u64 p23 = cload_u64((const u64*)(rs + 2));
            bool okA = ((p01 ^ etag) & emsk) == 0;
            bool okB = ((p23 ^ etag) & emsk) == 0;
            while (!__all(okA & okB)) {
                __builtin_amdgcn_s_sleep(1);
                if (!okA) {
                    p01 = cload_u64((const u64*)rs);
                    okA = ((p01 ^ etag) & emsk) == 0;
                }
                if (!okB) {
                    p23 = cload_u64((const u64*)(rs + 2));
                    okB = ((p23 ^ etag) & emsk) == 0;
                }
            }
            float4 v;
            v.x = half_to_f((u32)(p01 & 0xffffffffu));
            v.y = half_to_f((u32)(p01 >> 32));
            v.z = half_to_f((u32)(p23 & 0xffffffffu));
            v.w = half_to_f((u32)(p23 >> 32));
            *(float4*)&fl[ep] = v;
        } else {
            *(float4*)&fl[ep] = make_float4(0.f, 0.f, 0.f, 0.f);  // feats_{-1}=0
        }
        __syncthreads();  // (L) feats staged

        // ---- 2. matvec from LDS + fused readout partial ----
        float4 f0 = *(const float4*)&fl[kofs + 0 * 256];
        float4 f1 = *(const float4*)&fl[kofs + 1 * 256];
        float4 f2 = *(const float4*)&fl[kofs + 2 * 256];
        float4 f3 = *(const float4*)&fl[kofs + 3 * 256];

        float acc0 = 0.f, acc1 = 0.f, acc2 = 0.f, acc3 = 0.f;
#define DOT_STEP(i, fv) \
        acc0 += wreg[0][i].x * fv.x + wreg[0][i].y * fv.y + wreg[0][i].z * fv.z + wreg[0][i].w * fv.w; \
        acc1 += wreg[1][i].x * fv.x + wreg[1][i].y * fv.y + wreg[1][i].z * fv.z + wreg[1][i].w * fv.w; \
        acc2 += wreg[2][i].x * fv.x + wreg[2][i].y * fv.y + wreg[2][i].z * fv.z + wreg[2][i].w * fv.w; \
        acc3 += wreg[3][i].x * fv.x + wreg[3][i].y * fv.y + wreg[3][i].z * fv.z + wreg[3][i].w * fv.w;
        DOT_STEP(0, f0)
        DOT_STEP(1, f1)
        DOT_STEP(2, f2)
        DOT_STEP(3, f3)
#undef DOT_STEP

        float4 ra, rb;
        if (i0 == 0) { ra = f0; rb = f1; } else { ra = f2; rb = f3; }
        float p = wo0.x * ra.x + wo0.y * ra.y + wo0.z * ra.z + wo0.w * ra.w
                + wo1.x * rb.x + wo1.y * rb.y + wo1.z * rb.z + wo1.w * rb.w;

        // ---- 3. wave reduce, lane63 -> LDS (double-buffered by t&1) ----
        acc0 = wave_sum(acc0);
        acc1 = wave_sum(acc1);
        acc2 = wave_sum(acc2);
        acc3 = wave_sum(acc3);
        p    = wave_sum(p);
        const int pb = t & 1;
        if (lane == 63) {
            // one contiguous float4 write per wave
            *(float4*)&red[pb][w][0] = make_float4(acc0, acc1, acc2, acc3);
            redo[pb][w] = p;
        }
        if (w == 0) __builtin_amdgcn_s_setprio(1);  // priority through the tail
        __syncthreads();  // (A)

        // ---- 4. wave0: lane-parallel combine, clamp, coalesced publish ----
        if (w == 0 && t < T) {
            // lane L reads partial(row ((L>>2)&3)*4+(L&3), kg L>>4): coalesced
            float v = red[pb][lane >> 2][lane & 3];
            v += __shfl_xor(v, 16);   // fold k-groups
            v += __shfl_xor(v, 32);
            // lanes 0..15 now hold full row sums for rows 0..15
            float s = v + xval;
            s = fminf(1.f, fmaxf(-1.f, s));
            u32 hb = (u32)__builtin_bit_cast(u16, (_Float16)s);
            u32 pk = ((u32)(t + 1) << 16) | hb;
            if (lane < 16) {
                // 16 lanes, contiguous addresses -> one 64B transaction
                cstore_u32(ring + (size_t)(t & (K - 1)) * F + b * 16 + lane, pk);
            }
            __builtin_amdgcn_s_setprio(0);
            if (lane < 16) {
                const int tn = (t + 1 < T) ? (t + 1) : (T - 1);
                xval = x[(size_t)(b * 16 + lane) * T + tn];  // off critical path
            }
        } else if (w == 0) {
            __builtin_amdgcn_s_setprio(0);
        }

        // ---- 5. wave1: lane-parallel readout fold, store out[:, t-1] ----
        if (w == 1 && t > 0) {
            float v = redo[pb][lane & 15];
            v += __shfl_xor(v, 2);   // fold waves with same row parity (w&1)
            v += __shfl_xor(v, 4);
            v += __shfl_xor(v, 8);
            if (lane < 2)
                out[(size_t)(b * 2 + lane) * T + (t - 1)] = v;
        }
        // red/redo double-buffered; fl rewrite at t+1 separated by sync (A);
        // ring slot reuse: block publishes step t only after ALL blocks
        // published t-1 (lockstep), so oldest in-flight reads are step t-1
        // -> K>=2 safe, K=4 used. No capacity counters needed.
    }
}

extern "C" void kernel_launch(void* const* d_in, const int* in_sizes, int n_in,
                              void* d_out, int out_size, void* d_ws, size_t ws_size,
                              hipStream_t stream) {
    const float* x    = (const float*)d_in[0];
    const float* Wres = (const float*)d_in[1];
    const float* wout = (const float*)d_in[2];
    float* out        = (float*)d_out;
    u32* ring         = (u32*)((char*)d_ws + 4096);

    // no memset: ring tags are self-describing; 0xAA poison never matches.

    void* args[] = { (void*)&x, (void*)&Wres, (void*)&wout, (void*)&out,
                     (void*)&ring };
    (void)hipLaunchCooperativeKernel((const void*)rc_kernel, dim3(NBLK), dim3(NTHR),
                                     args, 0, stream);
}

// Round 5
// 6949.802 us; speedup vs baseline: 1.3081x; 1.1094x over previous
//
#include <hip/hip_runtime.h>

#define F     4096
#define T     2048
#define NBLK  256
#define NTHR  1024
#define K     4      // ring slots; lockstep bounds skew so K>=2 is safe

// d_ws layout (NOTHING memset; harness re-poisons d_ws to 0xAA each launch):
//   [4096, 4096 + K*F*4) : ring[K][4096] u32 pairs {tag u16 << 16 | f16 bits}.
//   Poison 0xAAAAAAAA -> tag 0xAAAA = 43690, never equals a real tag (1..2049).
//   Data IS the flag: a pair is valid iff its tag matches; producer stores are
//   fire-and-forget; consumers accept fresh chunks immediately (overlapped).
//
// SESSION RECORD (why this is the final form):
//   baseline (this file): 6958 us  (verified twice: 6969 prior session, 6958 r0)
//   R1 scattered 4B publishes w/ LDS-atomic combine: 9091 us (+30%, WRITE 2x)
//   R2 barrier-free all-wave LDS tag spin:           8053 us (+16%, 2.1e8 cfl)
//   R3 wave0-only spin replacing sync(A):            7899 us (+13.5%)
//   R4 baseline sched + lane-par combine + setprio:  7710 us (+11%)
// Lessons: (1) the single coalesced 16-lane publish is sacred; (2) s_barrier
// sleeping is cheap, spinning waves steal issue slots + fabric BW; (3) the
// 2-barrier schedule is a sharp convoy equilibrium -- even tail-only edits
// (shfl chains on the publish path, setprio) regress it by ~10x more than
// instruction arithmetic predicts. Step cadence ~3.4us is dominated by the
// inter-block coherence RT (publish -> IC -> remote poll detect), which no
// source-level restructuring tried here was able to shorten.

typedef unsigned long long u64;
typedef unsigned int u32;
typedef unsigned short u16;

template <int CTRL>
__device__ __forceinline__ float dpp_add(float x) {
    int xi = __builtin_bit_cast(int, x);
    int yi = __builtin_amdgcn_update_dpp(0, xi, CTRL, 0xf, 0xf, false);
    return x + __builtin_bit_cast(float, yi);
}

// Full wave64 sum; total lands in lane 63. VALU-only.
__device__ __forceinline__ float wave_sum(float x) {
    x = dpp_add<0x111>(x); // row_shr:1
    x = dpp_add<0x112>(x); // row_shr:2
    x = dpp_add<0x114>(x); // row_shr:4
    x = dpp_add<0x118>(x); // row_shr:8
    x = dpp_add<0x142>(x); // row_bcast:15
    x = dpp_add<0x143>(x); // row_bcast:31
    return x;
}

#define PIN4(v) asm volatile("" : "+v"((v).x), "+v"((v).y), "+v"((v).z), "+v"((v).w))

__device__ __forceinline__ u64 cload_u64(const u64* p) {
    return __hip_atomic_load(p, __ATOMIC_RELAXED, __HIP_MEMORY_SCOPE_AGENT);
}
__device__ __forceinline__ void cstore_u32(u32* p, u32 v) {
    __hip_atomic_store(p, v, __ATOMIC_RELAXED, __HIP_MEMORY_SCOPE_AGENT);
}

__device__ __forceinline__ float half_to_f(u32 bits) {
    return (float)__builtin_bit_cast(_Float16, (u16)(bits & 0xffffu));
}

__global__ __launch_bounds__(NTHR, 4) void rc_kernel(
    const float* __restrict__ x, const float* __restrict__ Wres,
    const float* __restrict__ wout, float* __restrict__ out,
    u32* __restrict__ ring)
{
    __shared__ __align__(16) float fl[F];     // staged feats vector (16 KB)
    __shared__ float red[2][16][4];           // double-buffered matvec partials
    __shared__ float redo[2][16];             // double-buffered readout partials

    const int tid  = threadIdx.x;
    const int b    = blockIdx.x;
    const int w    = tid >> 6;
    const int lane = tid & 63;
    const int wr   = w & 3;   // row-group (4 rows each)
    const int wk   = w >> 2;  // k-group (1024 k each)

    // ---- persistent W_res fragment: 4 rows x 16 k = 64 fp32 regs/lane ----
    const int row0 = b * 16 + wr * 4;
    const int kofs = wk * 1024 + lane * 4;
    float4 wreg[4][4];
#pragma unroll
    for (int j = 0; j < 4; ++j) {
        const float* wp = Wres + (size_t)(row0 + j) * F + kofs;
#pragma unroll
        for (int i = 0; i < 4; ++i)
            wreg[j][i] = *(const float4*)(wp + i * 256);
    }
#pragma unroll
    for (int j = 0; j < 4; ++j) {
        PIN4(wreg[j][0]); PIN4(wreg[j][1]); PIN4(wreg[j][2]); PIN4(wreg[j][3]);
    }

    // ---- persistent w_out fragment (fused readout): 8 fp32 regs/lane ----
    const int rrow = b * 2 + (wr & 1);
    const int i0   = (wr >> 1) * 2;
    const float* wop = wout + (size_t)rrow * F + kofs + i0 * 256;
    float4 wo0 = *(const float4*)(wop);
    float4 wo1 = *(const float4*)(wop + 256);
    PIN4(wo0); PIN4(wo1);

    // ---- x prefetch for step 0 ----
    float xval = 0.f;
    if (tid < 16) xval = x[(size_t)(b * 16 + tid) * T + 0];

    const int ep = w * 256 + lane * 4;  // this lane's chunk base (elements)

    for (int t = 0; t <= T; ++t) {
        // ---- 1. poll feats_{t-1} pairs (data-as-flag) and stage to LDS ----
        if (t > 0) {
            const u32* rs = ring + (size_t)((t - 1) & (K - 1)) * F + ep;
            const u32 tag = (u32)t;
            // two u64 loads = 4 packed pairs {tag16|f16}
            u64 p01 = cload_u64((const u64*)rs);
            u64 p23 = cload_u64((const u64*)(rs + 2));
            bool okA = ((u32)(p01 & 0xffffffffu) >> 16 == tag)
                     & ((u32)(p01 >> 32) >> 16 == tag);
            bool okB = ((u32)(p23 & 0xffffffffu) >> 16 == tag)
                     & ((u32)(p23 >> 32) >> 16 == tag);
            while (!__all(okA & okB)) {
                __builtin_amdgcn_s_sleep(1);
                if (!okA) {
                    p01 = cload_u64((const u64*)rs);
                    okA = ((u32)(p01 & 0xffffffffu) >> 16 == tag)
                        & ((u32)(p01 >> 32) >> 16 == tag);
                }
                if (!okB) {
                    p23 = cload_u64((const u64*)(rs + 2));
                    okB = ((u32)(p23 & 0xffffffffu) >> 16 == tag)
                        & ((u32)(p23 >> 32) >> 16 == tag);
                }
            }
            float4 v;
            v.x = half_to_f((u32)(p01 & 0xffffffffu));
            v.y = half_to_f((u32)(p01 >> 32));
            v.z = half_to_f((u32)(p23 & 0xffffffffu));
            v.w = half_to_f((u32)(p23 >> 32));
            *(float4*)&fl[ep] = v;
        } else {
            *(float4*)&fl[ep] = make_float4(0.f, 0.f, 0.f, 0.f);  // feats_{-1}=0
        }
        __syncthreads();  // (L) feats staged

        // ---- 2. matvec from LDS + fused readout partial ----
        float4 f0 = *(const float4*)&fl[kofs + 0 * 256];
        float4 f1 = *(const float4*)&fl[kofs + 1 * 256];
        float4 f2 = *(const float4*)&fl[kofs + 2 * 256];
        float4 f3 = *(const float4*)&fl[kofs + 3 * 256];

        float acc0 = 0.f, acc1 = 0.f, acc2 = 0.f, acc3 = 0.f;
#define DOT_STEP(i, fv) \
        acc0 += wreg[0][i].x * fv.x + wreg[0][i].y * fv.y + wreg[0][i].z * fv.z + wreg[0][i].w * fv.w; \
        acc1 += wreg[1][i].x * fv.x + wreg[1][i].y * fv.y + wreg[1][i].z * fv.z + wreg[1][i].w * fv.w; \
        acc2 += wreg[2][i].x * fv.x + wreg[2][i].y * fv.y + wreg[2][i].z * fv.z + wreg[2][i].w * fv.w; \
        acc3 += wreg[3][i].x * fv.x + wreg[3][i].y * fv.y + wreg[3][i].z * fv.z + wreg[3][i].w * fv.w;
        DOT_STEP(0, f0)
        DOT_STEP(1, f1)
        DOT_STEP(2, f2)
        DOT_STEP(3, f3)
#undef DOT_STEP

        float4 ra, rb;
        if (i0 == 0) { ra = f0; rb = f1; } else { ra = f2; rb = f3; }
        float p = wo0.x * ra.x + wo0.y * ra.y + wo0.z * ra.z + wo0.w * ra.w
                + wo1.x * rb.x + wo1.y * rb.y + wo1.z * rb.z + wo1.w * rb.w;

        // ---- 3. wave reduce, lane63 -> LDS (double-buffered by t&1) ----
        acc0 = wave_sum(acc0);
        acc1 = wave_sum(acc1);
        acc2 = wave_sum(acc2);
        acc3 = wave_sum(acc3);
        p    = wave_sum(p);
        const int pb = t & 1;
        if (lane == 63) {
            red[pb][w][0] = acc0; red[pb][w][1] = acc1;
            red[pb][w][2] = acc2; red[pb][w][3] = acc3;
            redo[pb][w] = p;
        }
        __syncthreads();  // (A)

        // ---- 4. wave 0: combine, clamp, publish packed pair (store = flag) ----
        if (w == 0 && t < T) {
            if (lane < 16) {
                const int r = lane, rw = r >> 2, rj = r & 3;
                float s = red[pb][rw][rj] + red[pb][rw + 4][rj]
                        + red[pb][rw + 8][rj] + red[pb][rw + 12][rj];
                s += xval;
                s = fminf(1.f, fmaxf(-1.f, s));
                u32 hb = (u32)__builtin_bit_cast(u16, (_Float16)s);
                u32 pk = ((u32)(t + 1) << 16) | hb;
                cstore_u32(ring + (size_t)(t & (K - 1)) * F + b * 16 + r, pk);
                const int tn = (t + 1 < T) ? (t + 1) : (T - 1);
                xval = x[(size_t)(b * 16 + lane) * T + tn];  // off critical path
            }
        }

        // ---- 5. out[:, t-1] store (wave 1; off the publish path) ----
        if (t > 0 && tid >= 64 && tid < 66) {
            const int r = tid - 64;
            float s = redo[pb][r]      + redo[pb][r + 2]  + redo[pb][r + 4]
                    + redo[pb][r + 6]  + redo[pb][r + 8]  + redo[pb][r + 10]
                    + redo[pb][r + 12] + redo[pb][r + 14];
            out[(size_t)(b * 2 + r) * T + (t - 1)] = s;
        }
        // red/redo double-buffered; fl rewrite at t+1 separated by sync (A);
        // ring slot reuse: block publishes step t only after ALL blocks
        // published t-1 (lockstep), so oldest in-flight reads are step t-1
        // -> K>=2 safe, K=4 used. No capacity counters needed.
    }
}

extern "C" void kernel_launch(void* const* d_in, const int* in_sizes, int n_in,
                              void* d_out, int out_size, void* d_ws, size_t ws_size,
                              hipStream_t stream) {
    const float* x    = (const float*)d_in[0];
    const float* Wres = (const float*)d_in[1];
    const float* wout = (const float*)d_in[2];
    float* out        = (float*)d_out;
    u32* ring         = (u32*)((char*)d_ws + 4096);

    // no memset: ring tags are self-describing; 0xAA poison never matches.

    void* args[] = { (void*)&x, (void*)&Wres, (void*)&wout, (void*)&out,
                     (void*)&ring };
    (void)hipLaunchCooperativeKernel((const void*)rc_kernel, dim3(NBLK), dim3(NTHR),
                                     args, 0, stream);
}

// Round 6
// 6603.422 us; speedup vs baseline: 1.3767x; 1.0525x over previous
//
#include <hip/hip_runtime.h>

#define F     4096
#define T     2048
#define NBLK  256
#define NTHR  1024
#define K     4      // ring slots; lockstep bounds skew so K>=2 is safe

// d_ws layout (NOTHING memset; harness re-poisons d_ws to 0xAA each launch):
//   [4096, 4096 + K*F*4) : ring[K][4096] u32 pairs {tag u16 << 16 | f16 bits}.
//   Poison 0xAAAAAAAA -> tag 0xAAAA = 43690, never equals a real tag (1..2049).
//   Data IS the flag: a pair is valid iff its tag matches; producer stores are
//   fire-and-forget; consumers accept fresh chunks immediately (overlapped).
//
// SESSION RECORD:
//   baseline: 6950-6969 us (verified 3x independently; spread <0.3%)
//   R1 scattered 4B publishes w/ LDS-atomic combine: 9091 us (+30%, WRITE 2x)
//   R2 barrier-free all-wave LDS tag spin:           8053 us (+16%, 2.1e8 cfl)
//   R3 wave0-only spin replacing sync(A):            7899 us (+13.5%)
//   R4 baseline sched + lane-par combine + setprio:  7710 us (+11%)
// Lessons: coalesced 16-lane publish is sacred; s_barrier sleep is cheap,
// spinning waves are expensive; the 2-barrier schedule is a sharp optimum.
//
// R6 (this file): ONLY change vs baseline = staging concentrated in waves 0-7
// (each polls 512 elems via 4 independent u64 loads/lane); waves 8-15 skip to
// sync(L) and sleep. Mechanism: halves concurrent IC poll streams during the
// publish-visibility window + halves independent detect max-draws per block.
// Publish path, barriers, matvec, reductions: byte-identical to baseline.

typedef unsigned long long u64;
typedef unsigned int u32;
typedef unsigned short u16;

template <int CTRL>
__device__ __forceinline__ float dpp_add(float x) {
    int xi = __builtin_bit_cast(int, x);
    int yi = __builtin_amdgcn_update_dpp(0, xi, CTRL, 0xf, 0xf, false);
    return x + __builtin_bit_cast(float, yi);
}

// Full wave64 sum; total lands in lane 63. VALU-only.
__device__ __forceinline__ float wave_sum(float x) {
    x = dpp_add<0x111>(x); // row_shr:1
    x = dpp_add<0x112>(x); // row_shr:2
    x = dpp_add<0x114>(x); // row_shr:4
    x = dpp_add<0x118>(x); // row_shr:8
    x = dpp_add<0x142>(x); // row_bcast:15
    x = dpp_add<0x143>(x); // row_bcast:31
    return x;
}

#define PIN4(v) asm volatile("" : "+v"((v).x), "+v"((v).y), "+v"((v).z), "+v"((v).w))

__device__ __forceinline__ u64 cload_u64(const u64* p) {
    return __hip_atomic_load(p, __ATOMIC_RELAXED, __HIP_MEMORY_SCOPE_AGENT);
}
__device__ __forceinline__ void cstore_u32(u32* p, u32 v) {
    __hip_atomic_store(p, v, __ATOMIC_RELAXED, __HIP_MEMORY_SCOPE_AGENT);
}

__device__ __forceinline__ float half_to_f(u32 bits) {
    return (float)__builtin_bit_cast(_Float16, (u16)(bits & 0xffffu));
}

__device__ __forceinline__ bool pair_ok(u64 p, u32 tag) {
    return ((u32)(p & 0xffffffffu) >> 16 == tag)
         & ((u32)(p >> 32) >> 16 == tag);
}

__global__ __launch_bounds__(NTHR, 4) void rc_kernel(
    const float* __restrict__ x, const float* __restrict__ Wres,
    const float* __restrict__ wout, float* __restrict__ out,
    u32* __restrict__ ring)
{
    __shared__ __align__(16) float fl[F];     // staged feats vector (16 KB)
    __shared__ float red[2][16][4];           // double-buffered matvec partials
    __shared__ float redo[2][16];             // double-buffered readout partials

    const int tid  = threadIdx.x;
    const int b    = blockIdx.x;
    const int w    = tid >> 6;
    const int lane = tid & 63;
    const int wr   = w & 3;   // row-group (4 rows each)
    const int wk   = w >> 2;  // k-group (1024 k each)

    // ---- persistent W_res fragment: 4 rows x 16 k = 64 fp32 regs/lane ----
    const int row0 = b * 16 + wr * 4;
    const int kofs = wk * 1024 + lane * 4;
    float4 wreg[4][4];
#pragma unroll
    for (int j = 0; j < 4; ++j) {
        const float* wp = Wres + (size_t)(row0 + j) * F + kofs;
#pragma unroll
        for (int i = 0; i < 4; ++i)
            wreg[j][i] = *(const float4*)(wp + i * 256);
    }
#pragma unroll
    for (int j = 0; j < 4; ++j) {
        PIN4(wreg[j][0]); PIN4(wreg[j][1]); PIN4(wreg[j][2]); PIN4(wreg[j][3]);
    }

    // ---- persistent w_out fragment (fused readout): 8 fp32 regs/lane ----
    const int rrow = b * 2 + (wr & 1);
    const int i0   = (wr >> 1) * 2;
    const float* wop = wout + (size_t)rrow * F + kofs + i0 * 256;
    float4 wo0 = *(const float4*)(wop);
    float4 wo1 = *(const float4*)(wop + 256);
    PIN4(wo0); PIN4(wo1);

    // ---- x prefetch for step 0 ----
    float xval = 0.f;
    if (tid < 16) xval = x[(size_t)(b * 16 + tid) * T + 0];

    // staging chunk base for waves 0..7: 512 elements per wave, 8 per lane
    const int ep8 = w * 512 + lane * 8;

    for (int t = 0; t <= T; ++t) {
        // ---- 1. waves 0-7 poll feats_{t-1} pairs and stage to LDS;
        //         waves 8-15 go straight to sync(L) and sleep (cheap) ----
        if (t > 0) {
            if (w < 8) {
                const u32* rs = ring + (size_t)((t - 1) & (K - 1)) * F + ep8;
                const u32 tag = (u32)t;
                // four independent u64 loads = 8 packed pairs {tag16|f16}
                u64 p0 = cload_u64((const u64*)rs);
                u64 p1 = cload_u64((const u64*)(rs + 2));
                u64 p2 = cload_u64((const u64*)(rs + 4));
                u64 p3 = cload_u64((const u64*)(rs + 6));
                bool ok0 = pair_ok(p0, tag), ok1 = pair_ok(p1, tag);
                bool ok2 = pair_ok(p2, tag), ok3 = pair_ok(p3, tag);
                while (!__all(ok0 & ok1 & ok2 & ok3)) {
                    __builtin_amdgcn_s_sleep(1);
                    if (!ok0) { p0 = cload_u64((const u64*)rs);       ok0 = pair_ok(p0, tag); }
                    if (!ok1) { p1 = cload_u64((const u64*)(rs + 2)); ok1 = pair_ok(p1, tag); }
                    if (!ok2) { p2 = cload_u64((const u64*)(rs + 4)); ok2 = pair_ok(p2, tag); }
                    if (!ok3) { p3 = cload_u64((const u64*)(rs + 6)); ok3 = pair_ok(p3, tag); }
                }
                float4 va, vb;
                va.x = half_to_f((u32)(p0 & 0xffffffffu));
                va.y = half_to_f((u32)(p0 >> 32));
                va.z = half_to_f((u32)(p1 & 0xffffffffu));
                va.w = half_to_f((u32)(p1 >> 32));
                vb.x = half_to_f((u32)(p2 & 0xffffffffu));
                vb.y = half_to_f((u32)(p2 >> 32));
                vb.z = half_to_f((u32)(p3 & 0xffffffffu));
                vb.w = half_to_f((u32)(p3 >> 32));
                *(float4*)&fl[ep8]     = va;
                *(float4*)&fl[ep8 + 4] = vb;
            }
        } else {
            if (w < 8) {  // feats_{-1} = 0
                *(float4*)&fl[ep8]     = make_float4(0.f, 0.f, 0.f, 0.f);
                *(float4*)&fl[ep8 + 4] = make_float4(0.f, 0.f, 0.f, 0.f);
            }
        }
        __syncthreads();  // (L) feats staged

        // ---- 2. matvec from LDS + fused readout partial ----
        float4 f0 = *(const float4*)&fl[kofs + 0 * 256];
        float4 f1 = *(const float4*)&fl[kofs + 1 * 256];
        float4 f2 = *(const float4*)&fl[kofs + 2 * 256];
        float4 f3 = *(const float4*)&fl[kofs + 3 * 256];

        float acc0 = 0.f, acc1 = 0.f, acc2 = 0.f, acc3 = 0.f;
#define DOT_STEP(i, fv) \
        acc0 += wreg[0][i].x * fv.x + wreg[0][i].y * fv.y + wreg[0][i].z * fv.z + wreg[0][i].w * fv.w; \
        acc1 += wreg[1][i].x * fv.x + wreg[1][i].y * fv.y + wreg[1][i].z * fv.z + wreg[1][i].w * fv.w; \
        acc2 += wreg[2][i].x * fv.x + wreg[2][i].y * fv.y + wreg[2][i].z * fv.z + wreg[2][i].w * fv.w; \
        acc3 += wreg[3][i].x * fv.x + wreg[3][i].y * fv.y + wreg[3][i].z * fv.z + wreg[3][i].w * fv.w;
        DOT_STEP(0, f0)
        DOT_STEP(1, f1)
        DOT_STEP(2, f2)
        DOT_STEP(3, f3)
#undef DOT_STEP

        float4 ra, rb;
        if (i0 == 0) { ra = f0; rb = f1; } else { ra = f2; rb = f3; }
        float p = wo0.x * ra.x + wo0.y * ra.y + wo0.z * ra.z + wo0.w * ra.w
                + wo1.x * rb.x + wo1.y * rb.y + wo1.z * rb.z + wo1.w * rb.w;

        // ---- 3. wave reduce, lane63 -> LDS (double-buffered by t&1) ----
        acc0 = wave_sum(acc0);
        acc1 = wave_sum(acc1);
        acc2 = wave_sum(acc2);
        acc3 = wave_sum(acc3);
        p    = wave_sum(p);
        const int pb = t & 1;
        if (lane == 63) {
            red[pb][w][0] = acc0; red[pb][w][1] = acc1;
            red[pb][w][2] = acc2; red[pb][w][3] = acc3;
            redo[pb][w] = p;
        }
        __syncthreads();  // (A)

        // ---- 4. wave 0: combine, clamp, publish packed pair (store = flag) ----
        if (w == 0 && t < T) {
            if (lane < 16) {
                const int r = lane, rw = r >> 2, rj = r & 3;
                float s = red[pb][rw][rj] + red[pb][rw + 4][rj]
                        + red[pb][rw + 8][rj] + red[pb][rw + 12][rj];
                s += xval;
                s = fminf(1.f, fmaxf(-1.f, s));
                u32 hb = (u32)__builtin_bit_cast(u16, (_Float16)s);
                u32 pk = ((u32)(t + 1) << 16) | hb;
                cstore_u32(ring + (size_t)(t & (K - 1)) * F + b * 16 + r, pk);
                const int tn = (t + 1 < T) ? (t + 1) : (T - 1);
                xval = x[(size_t)(b * 16 + lane) * T + tn];  // off critical path
            }
        }

        // ---- 5. out[:, t-1] store (wave 1; off the publish path) ----
        if (t > 0 && tid >= 64 && tid < 66) {
            const int r = tid - 64;
            float s = redo[pb][r]      + redo[pb][r + 2]  + redo[pb][r + 4]
                    + redo[pb][r + 6]  + redo[pb][r + 8]  + redo[pb][r + 10]
                    + redo[pb][r + 12] + redo[pb][r + 14];
            out[(size_t)(b * 2 + r) * T + (t - 1)] = s;
        }
        // red/redo double-buffered; fl rewrite at t+1 separated by sync (A);
        // ring slot reuse: block publishes step t only after ALL blocks
        // published t-1 (lockstep), so oldest in-flight reads are step t-1
        // -> K>=2 safe, K=4 used. No capacity counters needed.
    }
}

extern "C" void kernel_launch(void* const* d_in, const int* in_sizes, int n_in,
                              void* d_out, int out_size, void* d_ws, size_t ws_size,
                              hipStream_t stream) {
    const float* x    = (const float*)d_in[0];
    const float* Wres = (const float*)d_in[1];
    const float* wout = (const float*)d_in[2];
    float* out        = (float*)d_out;
    u32* ring         = (u32*)((char*)d_ws + 4096);

    // no memset: ring tags are self-describing; 0xAA poison never matches.

    void* args[] = { (void*)&x, (void*)&Wres, (void*)&wout, (void*)&out,
                     (void*)&ring };
    (void)hipLaunchCooperativeKernel((const void*)rc_kernel, dim3(NBLK), dim3(NTHR),
                                     args, 0, stream);
}

// Round 7
// 6458.894 us; speedup vs baseline: 1.4075x; 1.0224x over previous
//
#include <hip/hip_runtime.h>

#define F     4096
#define T     2048
#define NBLK  256
#define NTHR  1024
#define K     4      // ring slots; lockstep bounds skew so K>=2 is safe

// d_ws layout (NOTHING memset; harness re-poisons d_ws to 0xAA each launch):
//   [4096, 4096 + K*F*4) : ring[K][4096] u32 pairs {tag u16 << 16 | f16 bits}.
//   Poison 0xAAAAAAAA -> tag 0xAAAA = 43690, never equals a real tag (1..2049).
//   Data IS the flag: a pair is valid iff its tag matches; producer stores are
//   fire-and-forget; consumers accept fresh chunks immediately (overlapped).
//
// SESSION RECORD:
//   baseline 2-barrier/16-poller: 6950-6969 us (verified 3x, spread <0.3%)
//   R1 scattered 4B publishes:        9091 us (+30%, WRITE 2x)  [reverted]
//   R2 barrier-free all-wave spin:    8053 us (+16%)            [reverted]
//   R3 wave0-only spin, no sync(A):   7899 us (+13.5%)          [reverted]
//   R4 lane-par combine + setprio:    7710 us (+11%)            [reverted]
//   R6 staging in waves 0-7 only:     6603 us (-5%)  <- poll-contention WIN
// Lessons: coalesced 16-lane publish is sacred; s_barrier sleep is cheap,
// spinning waves are expensive; step cadence has a component proportional to
// concurrent poll streams during the publish-visibility window.
//
// R7 (this file): continue the R6 gradient. Staging in waves 0-3 only (one
// poller per SIMD), each polling 1024 elems via 8 independent u64 loads/lane.
// Staging LDS layout reshaped to 4 groups x 16B-stride writes per lane ->
// conflict-free (R6's 32B-stride writes cost 6.7e7 bank-conflict cycles).
// Publish path, barriers, matvec, reductions: byte-identical to baseline.

typedef unsigned long long u64;
typedef unsigned int u32;
typedef unsigned short u16;

template <int CTRL>
__device__ __forceinline__ float dpp_add(float x) {
    int xi = __builtin_bit_cast(int, x);
    int yi = __builtin_amdgcn_update_dpp(0, xi, CTRL, 0xf, 0xf, false);
    return x + __builtin_bit_cast(float, yi);
}

// Full wave64 sum; total lands in lane 63. VALU-only.
__device__ __forceinline__ float wave_sum(float x) {
    x = dpp_add<0x111>(x); // row_shr:1
    x = dpp_add<0x112>(x); // row_shr:2
    x = dpp_add<0x114>(x); // row_shr:4
    x = dpp_add<0x118>(x); // row_shr:8
    x = dpp_add<0x142>(x); // row_bcast:15
    x = dpp_add<0x143>(x); // row_bcast:31
    return x;
}

#define PIN4(v) asm volatile("" : "+v"((v).x), "+v"((v).y), "+v"((v).z), "+v"((v).w))

__device__ __forceinline__ u64 cload_u64(const u64* p) {
    return __hip_atomic_load(p, __ATOMIC_RELAXED, __HIP_MEMORY_SCOPE_AGENT);
}
__device__ __forceinline__ void cstore_u32(u32* p, u32 v) {
    __hip_atomic_store(p, v, __ATOMIC_RELAXED, __HIP_MEMORY_SCOPE_AGENT);
}

__device__ __forceinline__ float half_to_f(u32 bits) {
    return (float)__builtin_bit_cast(_Float16, (u16)(bits & 0xffffu));
}

__device__ __forceinline__ bool pair_ok(u64 p, u32 tag) {
    return ((u32)(p & 0xffffffffu) >> 16 == tag)
         & ((u32)(p >> 32) >> 16 == tag);
}

__device__ __forceinline__ float4 pairs_to_f4(u64 a, u64 b) {
    float4 v;
    v.x = half_to_f((u32)(a & 0xffffffffu));
    v.y = half_to_f((u32)(a >> 32));
    v.z = half_to_f((u32)(b & 0xffffffffu));
    v.w = half_to_f((u32)(b >> 32));
    return v;
}

__global__ __launch_bounds__(NTHR, 4) void rc_kernel(
    const float* __restrict__ x, const float* __restrict__ Wres,
    const float* __restrict__ wout, float* __restrict__ out,
    u32* __restrict__ ring)
{
    __shared__ __align__(16) float fl[F];     // staged feats vector (16 KB)
    __shared__ float red[2][16][4];           // double-buffered matvec partials
    __shared__ float redo[2][16];             // double-buffered readout partials

    const int tid  = threadIdx.x;
    const int b    = blockIdx.x;
    const int w    = tid >> 6;
    const int lane = tid & 63;
    const int wr   = w & 3;   // row-group (4 rows each)
    const int wk   = w >> 2;  // k-group (1024 k each)

    // ---- persistent W_res fragment: 4 rows x 16 k = 64 fp32 regs/lane ----
    const int row0 = b * 16 + wr * 4;
    const int kofs = wk * 1024 + lane * 4;
    float4 wreg[4][4];
#pragma unroll
    for (int j = 0; j < 4; ++j) {
        const float* wp = Wres + (size_t)(row0 + j) * F + kofs;
#pragma unroll
        for (int i = 0; i < 4; ++i)
            wreg[j][i] = *(const float4*)(wp + i * 256);
    }
#pragma unroll
    for (int j = 0; j < 4; ++j) {
        PIN4(wreg[j][0]); PIN4(wreg[j][1]); PIN4(wreg[j][2]); PIN4(wreg[j][3]);
    }

    // ---- persistent w_out fragment (fused readout): 8 fp32 regs/lane ----
    const int rrow = b * 2 + (wr & 1);
    const int i0   = (wr >> 1) * 2;
    const float* wop = wout + (size_t)rrow * F + kofs + i0 * 256;
    float4 wo0 = *(const float4*)(wop);
    float4 wo1 = *(const float4*)(wop + 256);
    PIN4(wo0); PIN4(wo1);

    // ---- x prefetch for step 0 ----
    float xval = 0.f;
    if (tid < 16) xval = x[(size_t)(b * 16 + tid) * T + 0];

    // staging base for waves 0..3: wave w owns elems [w*1024, w*1024+1024);
    // lane's group j = elems sb + j*256 .. +3  (16B-stride writes: no conflicts)
    const int sb = w * 1024 + lane * 4;

    for (int t = 0; t <= T; ++t) {
        // ---- 1. waves 0-3 poll feats_{t-1} pairs and stage to LDS;
        //         waves 4-15 go straight to sync(L) and sleep (cheap) ----
        if (t > 0) {
            if (w < 4) {
                const u32* rs = ring + (size_t)((t - 1) & (K - 1)) * F + sb;
                const u32 tag = (u32)t;
                // 8 independent u64 loads = 16 packed pairs {tag16|f16}
                u64 pa0 = cload_u64((const u64*)(rs));
                u64 pa1 = cload_u64((const u64*)(rs + 2));
                u64 pb0 = cload_u64((const u64*)(rs + 256));
                u64 pb1 = cload_u64((const u64*)(rs + 258));
                u64 pc0 = cload_u64((const u64*)(rs + 512));
                u64 pc1 = cload_u64((const u64*)(rs + 514));
                u64 pd0 = cload_u64((const u64*)(rs + 768));
                u64 pd1 = cload_u64((const u64*)(rs + 770));
                bool oka = pair_ok(pa0, tag) & pair_ok(pa1, tag);
                bool okb = pair_ok(pb0, tag) & pair_ok(pb1, tag);
                bool okc = pair_ok(pc0, tag) & pair_ok(pc1, tag);
                bool okd = pair_ok(pd0, tag) & pair_ok(pd1, tag);
                while (!__all(oka & okb & okc & okd)) {
                    __builtin_amdgcn_s_sleep(1);
                    if (!oka) {
                        pa0 = cload_u64((const u64*)(rs));
                        pa1 = cload_u64((const u64*)(rs + 2));
                        oka = pair_ok(pa0, tag) & pair_ok(pa1, tag);
                    }
                    if (!okb) {
                        pb0 = cload_u64((const u64*)(rs + 256));
                        pb1 = cload_u64((const u64*)(rs + 258));
                        okb = pair_ok(pb0, tag) & pair_ok(pb1, tag);
                    }
                    if (!okc) {
                        pc0 = cload_u64((const u64*)(rs + 512));
                        pc1 = cload_u64((const u64*)(rs + 514));
                        okc = pair_ok(pc0, tag) & pair_ok(pc1, tag);
                    }
                    if (!okd) {
                        pd0 = cload_u64((const u64*)(rs + 768));
                        pd1 = cload_u64((const u64*)(rs + 770));
                        okd = pair_ok(pd0, tag) & pair_ok(pd1, tag);
                    }
                }
                *(float4*)&fl[sb]       = pairs_to_f4(pa0, pa1);
                *(float4*)&fl[sb + 256] = pairs_to_f4(pb0, pb1);
                *(float4*)&fl[sb + 512] = pairs_to_f4(pc0, pc1);
                *(float4*)&fl[sb + 768] = pairs_to_f4(pd0, pd1);
            }
        } else {
            if (w < 4) {  // feats_{-1} = 0
                const float4 z = make_float4(0.f, 0.f, 0.f, 0.f);
                *(float4*)&fl[sb]       = z;
                *(float4*)&fl[sb + 256] = z;
                *(float4*)&fl[sb + 512] = z;
                *(float4*)&fl[sb + 768] = z;
            }
        }
        __syncthreads();  // (L) feats staged

        // ---- 2. matvec from LDS + fused readout partial ----
        float4 f0 = *(const float4*)&fl[kofs + 0 * 256];
        float4 f1 = *(const float4*)&fl[kofs + 1 * 256];
        float4 f2 = *(const float4*)&fl[kofs + 2 * 256];
        float4 f3 = *(const float4*)&fl[kofs + 3 * 256];

        float acc0 = 0.f, acc1 = 0.f, acc2 = 0.f, acc3 = 0.f;
#define DOT_STEP(i, fv) \
        acc0 += wreg[0][i].x * fv.x + wreg[0][i].y * fv.y + wreg[0][i].z * fv.z + wreg[0][i].w * fv.w; \
        acc1 += wreg[1][i].x * fv.x + wreg[1][i].y * fv.y + wreg[1][i].z * fv.z + wreg[1][i].w * fv.w; \
        acc2 += wreg[2][i].x * fv.x + wreg[2][i].y * fv.y + wreg[2][i].z * fv.z + wreg[2][i].w * fv.w; \
        acc3 += wreg[3][i].x * fv.x + wreg[3][i].y * fv.y + wreg[3][i].z * fv.z + wreg[3][i].w * fv.w;
        DOT_STEP(0, f0)
        DOT_STEP(1, f1)
        DOT_STEP(2, f2)
        DOT_STEP(3, f3)
#undef DOT_STEP

        float4 ra, rb;
        if (i0 == 0) { ra = f0; rb = f1; } else { ra = f2; rb = f3; }
        float p = wo0.x * ra.x + wo0.y * ra.y + wo0.z * ra.z + wo0.w * ra.w
                + wo1.x * rb.x + wo1.y * rb.y + wo1.z * rb.z + wo1.w * rb.w;

        // ---- 3. wave reduce, lane63 -> LDS (double-buffered by t&1) ----
        acc0 = wave_sum(acc0);
        acc1 = wave_sum(acc1);
        acc2 = wave_sum(acc2);
        acc3 = wave_sum(acc3);
        p    = wave_sum(p);
        const int pb = t & 1;
        if (lane == 63) {
            red[pb][w][0] = acc0; red[pb][w][1] = acc1;
            red[pb][w][2] = acc2; red[pb][w][3] = acc3;
            redo[pb][w] = p;
        }
        __syncthreads();  // (A)

        // ---- 4. wave 0: combine, clamp, publish packed pair (store = flag) ----
        if (w == 0 && t < T) {
            if (lane < 16) {
                const int r = lane, rw = r >> 2, rj = r & 3;
                float s = red[pb][rw][rj] + red[pb][rw + 4][rj]
                        + red[pb][rw + 8][rj] + red[pb][rw + 12][rj];
                s += xval;
                s = fminf(1.f, fmaxf(-1.f, s));
                u32 hb = (u32)__builtin_bit_cast(u16, (_Float16)s);
                u32 pk = ((u32)(t + 1) << 16) | hb;
                cstore_u32(ring + (size_t)(t & (K - 1)) * F + b * 16 + r, pk);
                const int tn = (t + 1 < T) ? (t + 1) : (T - 1);
                xval = x[(size_t)(b * 16 + lane) * T + tn];  // off critical path
            }
        }

        // ---- 5. out[:, t-1] store (wave 1; off the publish path) ----
        if (t > 0 && tid >= 64 && tid < 66) {
            const int r = tid - 64;
            float s = redo[pb][r]      + redo[pb][r + 2]  + redo[pb][r + 4]
                    + redo[pb][r + 6]  + redo[pb][r + 8]  + redo[pb][r + 10]
                    + redo[pb][r + 12] + redo[pb][r + 14];
            out[(size_t)(b * 2 + r) * T + (t - 1)] = s;
        }
        // red/redo double-buffered; fl rewrite at t+1 separated by sync (A);
        // ring slot reuse: block publishes step t only after ALL blocks
        // published t-1 (lockstep), so oldest in-flight reads are step t-1
        // -> K>=2 safe, K=4 used. No capacity counters needed.
    }
}

extern "C" void kernel_launch(void* const* d_in, const int* in_sizes, int n_in,
                              void* d_out, int out_size, void* d_ws, size_t ws_size,
                              hipStream_t stream) {
    const float* x    = (const float*)d_in[0];
    const float* Wres = (const float*)d_in[1];
    const float* wout = (const float*)d_in[2];
    float* out        = (float*)d_out;
    u32* ring         = (u32*)((char*)d_ws + 4096);

    // no memset: ring tags are self-describing; 0xAA poison never matches.

    void* args[] = { (void*)&x, (void*)&Wres, (void*)&wout, (void*)&out,
                     (void*)&ring };
    (void)hipLaunchCooperativeKernel((const void*)rc_kernel, dim3(NBLK), dim3(NTHR),
                                     args, 0, stream);
}